// Round 13
// baseline (177.946 us; speedup 1.0000x reference)
//
#include <hip/hip_runtime.h>
#include <hip/hip_bf16.h>

#define D_IN  768
#define D_E   256
#define M_TOT 512      // B*S
#define E_TOT 100000

typedef __attribute__((ext_vector_type(4))) float f32x4;
typedef __attribute__((ext_vector_type(8))) short bf16x8;

__device__ __forceinline__ unsigned short bf16bits(float f) {
    union { __hip_bfloat16 h; unsigned short u; } c;
    c.h = __float2bfloat16(f);
    return c.u;
}

// ---------------------------------------------------------------------------
// Fused prep+proj (unchanged — at BW floor):
//   blocks [0,64):    proj  qb[m][e] = bf16(tanh(x@W^T+b)/||row||)
//   blocks [64,1627): prep  eb[n][k] = bf16(en[n][k]/||en[n]||)
// ---------------------------------------------------------------------------
#define PROJ_BLOCKS 64
#define PREP_BLOCKS 1563
#define PP_GRID (PROJ_BLOCKS + PREP_BLOCKS)
#define PTM 8
#define PBK 64
#define PROUNDS (D_IN / PBK)             // 12

__global__ __launch_bounds__(512) void fused_pp(
    const float* __restrict__ x, const float* __restrict__ W,
    const float* __restrict__ b, const float* __restrict__ en,
    unsigned short* __restrict__ qb, unsigned short* __restrict__ eb)
{
    __shared__ float ws[D_E * (PBK + 1)];
    __shared__ float xs[PTM][PBK];
    __shared__ float red[PTM][4];
    __shared__ float qiv[PTM];

    const int t   = threadIdx.x;
    const int bid = blockIdx.x;

    if (bid >= PROJ_BLOCKS) {
        const int lane = t & 63;
        const int gw   = (bid - PROJ_BLOCKS) * 8 + (t >> 6);
        #pragma unroll 2
        for (int i = 0; i < 8; ++i) {
            const int row = gw * 8 + i;
            if (row >= E_TOT) break;
            const float4 v = *reinterpret_cast<const float4*>(
                en + (size_t)row * D_E + lane * 4);
            float s = v.x*v.x + v.y*v.y + v.z*v.z + v.w*v.w;
            #pragma unroll
            for (int off = 1; off < 64; off <<= 1) s += __shfl_xor(s, off, 64);
            const float sc = 1.0f / fmaxf(sqrtf(s), 1e-8f);
            union { unsigned short u[4]; uint2 d; } o;
            o.u[0] = bf16bits(v.x * sc); o.u[1] = bf16bits(v.y * sc);
            o.u[2] = bf16bits(v.z * sc); o.u[3] = bf16bits(v.w * sc);
            *reinterpret_cast<uint2*>(eb + (size_t)row * D_E + lane * 4) = o.d;
        }
        return;
    }

    const int m0   = bid * PTM;
    const int e    = t & 255;
    const int half = t >> 8;
    const int c4   = t & 15;
    const int rr   = t >> 4;

    float4 wreg[8];
    float  xreg = 0.f;
    float  acc[4] = {0.f, 0.f, 0.f, 0.f};

    #pragma unroll
    for (int i = 0; i < 8; ++i)
        wreg[i] = *reinterpret_cast<const float4*>(
            &W[(size_t)(i * 32 + rr) * D_IN + c4 * 4]);
    xreg = x[(size_t)(m0 + (t >> 6)) * D_IN + (t & 63)];

    for (int rd = 0; rd < PROUNDS; ++rd) {
        #pragma unroll
        for (int i = 0; i < 8; ++i) {
            float* dst = &ws[(i * 32 + rr) * (PBK + 1) + c4 * 4];
            dst[0] = wreg[i].x; dst[1] = wreg[i].y;
            dst[2] = wreg[i].z; dst[3] = wreg[i].w;
        }
        xs[t >> 6][t & 63] = xreg;
        __syncthreads();
        if (rd + 1 < PROUNDS) {
            const int k0 = (rd + 1) * PBK;
            #pragma unroll
            for (int i = 0; i < 8; ++i)
                wreg[i] = *reinterpret_cast<const float4*>(
                    &W[(size_t)(i * 32 + rr) * D_IN + k0 + c4 * 4]);
            xreg = x[(size_t)(m0 + (t >> 6)) * D_IN + k0 + (t & 63)];
        }
        #pragma unroll
        for (int k = 0; k < PBK; ++k) {
            const float wv = ws[e * (PBK + 1) + k];
            #pragma unroll
            for (int j = 0; j < 4; ++j)
                acc[j] = fmaf(xs[half * 4 + j][k], wv, acc[j]);
        }
        __syncthreads();
    }

    const float bias = b[e];
    const int wv4 = (t >> 6) & 3;
    const int lane = t & 63;
    float q[4];
    #pragma unroll
    for (int j = 0; j < 4; ++j) {
        q[j] = tanhf(acc[j] + bias);
        float s = q[j] * q[j];
        #pragma unroll
        for (int off = 1; off < 64; off <<= 1) s += __shfl_xor(s, off, 64);
        if (lane == 0) red[half * 4 + j][wv4] = s;
    }
    __syncthreads();
    if (t < PTM) {
        const float s = red[t][0] + red[t][1] + red[t][2] + red[t][3];
        qiv[t] = 1.0f / fmaxf(sqrtf(s), 1e-8f);
    }
    __syncthreads();
    #pragma unroll
    for (int j = 0; j < 4; ++j)
        qb[(size_t)(m0 + half * 4 + j) * D_E + e] =
            bf16bits(q[j] * qiv[half * 4 + j]);
}

// ---------------------------------------------------------------------------
// Kernel 2 (v13): ZERO barriers, ZERO LDS in the main loop. Per-wave private
// pipeline. Wave = 32m x 32n; block = 4 waves = 64m x 64n; TPB=25 n-tiles.
// q panel: 16 bf16x8 frags loaded ONCE from L2-resident qb, pinned in regs
// via asm (defeats the r4/r5 rematerialization — check VGPR_Count ~160).
// Entities: global->reg half-tile chunks (ca=ks0-3, cb=ks4-7), reloaded for
// tile t+1 right after consumption -> compiler emits counted vmcnt (never a
// barrier-forced vmcnt(0)). Stores predicated, never waited on.
// Grid 504 = 8 m-groups x 63 n-groups, all co-resident; XCD-chunked so the
// 8 m-blocks sharing an eb slice live on one XCD's L2.
// ---------------------------------------------------------------------------
#define TPB 25
#define NGRPN 63                        // 63*25*64 = 100800 >= 100000
#define SIM_GRID (8 * NGRPN)            // 504

__device__ __forceinline__ f32x4 mfma16(bf16x8 a, bf16x8 b, f32x4 c) {
    return __builtin_amdgcn_mfma_f32_16x16x32_bf16(a, b, c, 0, 0, 0);
}

__global__ __launch_bounds__(256, 3) void sim_kernel(
    const unsigned short* __restrict__ eb, const unsigned short* __restrict__ qb,
    float* __restrict__ out)
{
    const int t    = threadIdx.x;
    const int lane = t & 63;
    const int wid  = t >> 6;        // 0..3
    const int l15  = lane & 15;
    const int lk   = lane >> 4;     // 0..3
    const int wm   = (wid >> 1) * 32;   // 0,32
    const int wn   = (wid & 1) * 32;    // 0,32

    // chunked XCD swizzle (504 = 8*63, %8==0 -> bijective)
    const int vbid  = (blockIdx.x & 7) * NGRPN + (blockIdx.x >> 3);
    const int mg    = vbid & 7;         // 8 m-blocks of one n-group adjacent
    const int ngrp  = vbid >> 3;        // 0..62
    const int m0    = mg * 64;
    const int nbase = ngrp * (TPB * 64);

    // ---- q panel: 16 frags from global (L2-resident), pinned in regs ----
    bf16x8 qf[2][8];
    #pragma unroll
    for (int mf = 0; mf < 2; ++mf)
        #pragma unroll
        for (int ks = 0; ks < 8; ++ks)
            qf[mf][ks] = *reinterpret_cast<const bf16x8*>(
                qb + (size_t)(m0 + wm + mf * 16 + l15) * D_E + ks * 32 + lk * 8);
    #pragma unroll
    for (int mf = 0; mf < 2; ++mf)
        #pragma unroll
        for (int ks = 0; ks < 8; ++ks)
            asm volatile("" : "+v"(qf[mf][ks]));   // pin: no remat into loop

    // entity frag address for (tile, nf); per-lane row clamp
    const unsigned short* ebl = eb + (size_t)lk * 8;   // k-chunk offset
    #define EADDR(tt, nf) ({                                                  \
        int n_ = nbase + (tt) * 64 + wn + (nf) * 16 + l15;                    \
        if (n_ >= E_TOT) n_ = E_TOT - 1;                                      \
        ebl + (size_t)n_ * D_E; })

    // ---- preload tile 0 (ca = ks0..3, cb = ks4..7) ----
    bf16x8 ca[2][4], cb[2][4];
    #pragma unroll
    for (int nf = 0; nf < 2; ++nf) {
        const unsigned short* p = EADDR(0, nf);
        #pragma unroll
        for (int kk = 0; kk < 4; ++kk) {
            ca[nf][kk] = *reinterpret_cast<const bf16x8*>(p + kk * 32);
            cb[nf][kk] = *reinterpret_cast<const bf16x8*>(p + 128 + kk * 32);
        }
    }

    for (int tt = 0; tt < TPB; ++tt) {
        f32x4 acc[2][2];
        #pragma unroll
        for (int mf = 0; mf < 2; ++mf)
            #pragma unroll
            for (int nf = 0; nf < 2; ++nf)
                acc[mf][nf] = (f32x4){0.f, 0.f, 0.f, 0.f};

        // phase 1: ks0..3 from ca (compiler inserts counted vmcnt for ca)
        __builtin_amdgcn_s_setprio(1);
        #pragma unroll
        for (int kk = 0; kk < 4; ++kk)
            #pragma unroll
            for (int mf = 0; mf < 2; ++mf) {
                acc[mf][0] = mfma16(ca[0][kk], qf[mf][kk], acc[mf][0]);
                acc[mf][1] = mfma16(ca[1][kk], qf[mf][kk], acc[mf][1]);
            }
        __builtin_amdgcn_s_setprio(0);

        // reload ca <- tile tt+1 ks0..3 (regs free; latency hides under cb)
        if (tt + 1 < TPB) {
            #pragma unroll
            for (int nf = 0; nf < 2; ++nf) {
                const unsigned short* p = EADDR(tt + 1, nf);
                #pragma unroll
                for (int kk = 0; kk < 4; ++kk)
                    ca[nf][kk] = *reinterpret_cast<const bf16x8*>(p + kk * 32);
            }
        }

        // phase 2: ks4..7 from cb
        __builtin_amdgcn_s_setprio(1);
        #pragma unroll
        for (int kk = 0; kk < 4; ++kk)
            #pragma unroll
            for (int mf = 0; mf < 2; ++mf) {
                acc[mf][0] = mfma16(cb[0][kk], qf[mf][kk + 4], acc[mf][0]);
                acc[mf][1] = mfma16(cb[1][kk], qf[mf][kk + 4], acc[mf][1]);
            }
        __builtin_amdgcn_s_setprio(0);

        // reload cb <- tile tt+1 ks4..7
        if (tt + 1 < TPB) {
            #pragma unroll
            for (int nf = 0; nf < 2; ++nf) {
                const unsigned short* p = EADDR(tt + 1, nf);
                #pragma unroll
                for (int kk = 0; kk < 4; ++kk)
                    cb[nf][kk] = *reinterpret_cast<const bf16x8*>(p + 128 + kk * 32);
            }
        }

        // stores: fire-and-forget, drain during later tiles
        const int n0t = nbase + tt * 64;
        #pragma unroll
        for (int mf = 0; mf < 2; ++mf) {
            const int m = m0 + wm + mf * 16 + l15;
            #pragma unroll
            for (int nf = 0; nf < 2; ++nf) {
                const int n = n0t + wn + nf * 16 + lk * 4;
                if (n < E_TOT)      // E%4==0 -> whole f32x4 valid
                    *reinterpret_cast<f32x4*>(&out[(size_t)m * E_TOT + n]) =
                        acc[mf][nf];
            }
        }
    }
    #undef EADDR
}

// ---------------------------------------------------------------------------
extern "C" void kernel_launch(void* const* d_in, const int* in_sizes, int n_in,
                              void* d_out, int out_size, void* d_ws, size_t ws_size,
                              hipStream_t stream) {
    const float* x  = (const float*)d_in[0];   // [4,128,768]
    const float* W  = (const float*)d_in[1];   // [256,768]
    const float* b  = (const float*)d_in[2];   // [256]
    const float* en = (const float*)d_in[3];   // [100000,256]
    float* out = (float*)d_out;                // [512,100000]

    unsigned short* qb = (unsigned short*)d_ws;                 // 256 KB
    unsigned short* eb = (unsigned short*)((char*)d_ws + (size_t)M_TOT * D_E * 2);

    fused_pp<<<PP_GRID, 512, 0, stream>>>(x, W, b, en, qb, eb); // 1627 blocks
    sim_kernel<<<SIM_GRID, 256, 0, stream>>>(eb, qb, out);      // 504 blocks
}